// Round 11
// baseline (199.104 us; speedup 1.0000x reference)
//
#include <hip/hip_runtime.h>
#include <hip/hip_bf16.h>

#define NCH 256      // C
#define NHD 8        // heads
#define HD 32        // head dim
#define NPIX 2304    // 48*48
#define H1DIM 512

typedef __attribute__((ext_vector_type(8))) __bf16 bf16x8;
typedef __attribute__((ext_vector_type(4))) float f32x4;

// ---------------- fused qk+v conv v2: prep folded in ------------------------
// blocks [0,3456): conv, head-pinned (bid&7 = head), identical task mapping
//   to qkv_k, but A-fragments are built DIRECTLY from NCHW f32 x (8 channel-
//   strided loads per fragment, independent -> 1 latency exposure; all 12
//   (b,sub) repeats of a pixel slice land on the same XCD -> L2-hits after
//   first touch) and qk/v weights are cast inline from f32 (2 adjacent 16B
//   loads per fragment). Same (__bf16) RNE casts prep used -> bit-identical.
// blocks [3456,3776): cast mlp-tail weights (pj_w|f1_w|f2_w) -> Wall bf16,
//   so mlp_k (the latency-invariant kernel) stays byte-for-byte untouched.
__global__ __launch_bounds__(256) void qkv2_k(
    const float* __restrict__ x, const float* __restrict__ qk_w,
    const float* __restrict__ v_w, const float* __restrict__ qk_b,
    const float* __restrict__ v_b,
    const float* __restrict__ pj_w, const float* __restrict__ f1_w,
    const float* __restrict__ f2_w,
    __bf16* __restrict__ Qb, __bf16* __restrict__ Kf,
    float* __restrict__ v_bu, __bf16* __restrict__ Vf,
    __bf16* __restrict__ Wall) {
    const int tid = threadIdx.x;
    if (blockIdx.x >= 3456) {
        // ---- mlp-tail weight cast: 81920 float4 over 320 blocks ----
        int i = ((int)blockIdx.x - 3456) * 256 + tid;
        const float* src; int off;
        if (i < 16384)      { src = pj_w; off = i; }
        else if (i < 49152) { src = f1_w; off = i - 16384; }
        else                { src = f2_w; off = i - 49152; }
        float4 v = ((const float4*)src)[off];
        union { __bf16 h[4]; uint2 u; } pk;
        pk.h[0] = (__bf16)v.x; pk.h[1] = (__bf16)v.y;
        pk.h[2] = (__bf16)v.z; pk.h[3] = (__bf16)v.w;
        ((uint2*)Wall)[i] = pk.u;
        return;
    }
    const int wave = tid >> 6, lane = tid & 63;
    const int l16 = lane & 15, quad = lane >> 4;
    const int h = blockIdx.x & 7;
    const int u = blockIdx.x >> 3;        // [0,432)
    const int tau = u * 4 + wave;         // [0,1728)
    const int px = tau % 144;
    const int rest = tau / 144;           // [0,12)
    const int b = rest & 1;
    const int sub = rest >> 1;            // [0,6)
    const int m0 = px * 16;
    const bool isv = sub >= 4;
    const int oc0 = isv ? (32 * h + 16 * (sub - 4)) : (64 * h + 16 * sub);
    const float* W32 = isv ? v_w : qk_w;

    // A source: x[b][c][m0+l16], c = quad*8 + k + j  (NPIX-strided channels)
    const float* xa = x + (size_t)b * NCH * NPIX + m0 + l16 + (size_t)(quad * 8) * NPIX;
    const float* wp = W32 + (size_t)(oc0 + l16) * NCH + quad * 8;

    f32x4 acc = {0.f, 0.f, 0.f, 0.f};
#pragma unroll
    for (int k = 0; k < NCH; k += 32) {
        const float* xp = xa + (size_t)k * NPIX;
        bf16x8 af;
#pragma unroll
        for (int j = 0; j < 8; ++j) af[j] = (__bf16)xp[(size_t)j * NPIX];
        float4 w0 = *(const float4*)(wp + k);
        float4 w1 = *(const float4*)(wp + k + 4);
        bf16x8 bf;
        bf[0] = (__bf16)w0.x; bf[1] = (__bf16)w0.y;
        bf[2] = (__bf16)w0.z; bf[3] = (__bf16)w0.w;
        bf[4] = (__bf16)w1.x; bf[5] = (__bf16)w1.y;
        bf[6] = (__bf16)w1.z; bf[7] = (__bf16)w1.w;
        acc = __builtin_amdgcn_mfma_f32_16x16x32_bf16(af, bf, acc, 0, 0, 0);
    }

    const int oc = oc0 + l16;
    const int mb = m0 + quad * 4;

    if (!isv) {
        const float bb = qk_b[oc];
        const int bh = b * NHD + h;
        const int dd = (oc0 & 16) + l16;
        if ((oc0 & 32) == 0) {
            const float qs = 0.17677669529663689f * 1.4426950408889634f;  // hd^-0.5 * log2e
#pragma unroll
            for (int r = 0; r < 4; ++r)
                Qb[((size_t)bh * NPIX + mb + r) * 32 + dd] = (__bf16)((acc[r] + bb) * qs);
        } else {
            __bf16* kp = Kf + ((size_t)(bh * 144 + px) * 64 + (dd >> 3) * 16 + quad * 4) * 8 + (dd & 7);
#pragma unroll
            for (int r = 0; r < 4; ++r) kp[r * 8] = (__bf16)(acc[r] + bb);
        }
    } else {
        const float bb = v_b[oc];
        const int bh = b * NHD + h;
        const int half = (oc0 >> 4) & 1;
        const size_t fb = ((size_t)b * NCH + oc) * NPIX + mb;
        float4 vf_; float* vp = &vf_.x;
        union { __bf16 hh[4]; uint2 u; } pk;
#pragma unroll
        for (int r = 0; r < 4; ++r) {
            float v = acc[r] + bb;
            vp[r] = v; pk.hh[r] = (__bf16)v;
        }
        *(float4*)&v_bu[fb] = vf_;
        *(uint2*)&Vf[((size_t)(bh * 144 + px) * 64 + lane) * 8 + half * 4] = pk.u;
    }
}

// ---------------- MFMA flash attention v9: key-split 4 (R10 best) -----------
__global__ __launch_bounds__(256) void attn9_k(const __bf16* __restrict__ Qb,
                                               const __bf16* __restrict__ Kf,
                                               const __bf16* __restrict__ Vf,
                                               const float* __restrict__ v_bu,
                                               const float* __restrict__ pe_w,
                                               const float* __restrict__ pe_b,
                                               __bf16* __restrict__ opb) {
    const int tid = threadIdx.x;
    const int wave = tid >> 6, lane = tid & 63;
    const int l16 = lane & 15, quad = lane >> 4;
    const int h = blockIdx.x & 7;
    const int r0 = (int)blockIdx.x >> 3;   // [0,144)
    const int qt = r0 % 72;
    const int b = r0 / 72;
    const int qb = qt * 32;
    const int bh = b * NHD + h;

    __shared__ float o_s[4][32][33];   // [wave][d][q], pad 33
    __shared__ float l_s[4][32];       // [wave][q]

    bf16x8 b_q0 = *(const bf16x8*)(Qb + ((size_t)bh * NPIX + qb + l16) * 32 + quad * 8);
    bf16x8 b_q1 = *(const bf16x8*)(Qb + ((size_t)bh * NPIX + qb + 16 + l16) * 32 + quad * 8);

    const __bf16* kf = Kf + ((size_t)(bh * 144 + wave * 36) * 64 + lane) * 8;
    const __bf16* vf = Vf + ((size_t)(bh * 144 + wave * 36) * 64 + lane) * 8;

    f32x4 o00 = {0.f,0.f,0.f,0.f}, o01 = {0.f,0.f,0.f,0.f};
    f32x4 o10 = {0.f,0.f,0.f,0.f}, o11 = {0.f,0.f,0.f,0.f};
    f32x4 l0 = {0.f,0.f,0.f,0.f}, l1 = {0.f,0.f,0.f,0.f};

#pragma unroll 3
    for (int t = 0; t < 36; ++t) {
        bf16x8 a_k = *(const bf16x8*)(kf + (size_t)t * 512);
        bf16x8 va  = *(const bf16x8*)(vf + (size_t)t * 512);
        f32x4 z = {0.f, 0.f, 0.f, 0.f};
        __builtin_amdgcn_s_setprio(1);
        f32x4 s0 = __builtin_amdgcn_mfma_f32_16x16x32_bf16(a_k, b_q0, z, 0, 0, 0);
        f32x4 s1 = __builtin_amdgcn_mfma_f32_16x16x32_bf16(a_k, b_q1, z, 0, 0, 0);
        __builtin_amdgcn_s_setprio(0);
        f32x4 p0, p1;
#pragma unroll
        for (int r = 0; r < 4; ++r) {
            p0[r] = __builtin_amdgcn_exp2f(s0[r]);
            p1[r] = __builtin_amdgcn_exp2f(s1[r]);
        }
        l0 += p0; l1 += p1;
        bf16x8 b0lo = {}, b0hi = {}, b1lo = {}, b1hi = {};
#pragma unroll
        for (int r = 0; r < 4; ++r) {
            __bf16 c0 = (__bf16)p0[r], c1 = (__bf16)p1[r];
            b0lo[r] = c0; b0hi[4 + r] = c0;
            b1lo[r] = c1; b1hi[4 + r] = c1;
        }
        __builtin_amdgcn_s_setprio(1);
        o00 = __builtin_amdgcn_mfma_f32_16x16x32_bf16(va, b0lo, o00, 0, 0, 0);
        o01 = __builtin_amdgcn_mfma_f32_16x16x32_bf16(va, b0hi, o01, 0, 0, 0);
        o10 = __builtin_amdgcn_mfma_f32_16x16x32_bf16(va, b1lo, o10, 0, 0, 0);
        o11 = __builtin_amdgcn_mfma_f32_16x16x32_bf16(va, b1hi, o11, 0, 0, 0);
        __builtin_amdgcn_s_setprio(0);
    }

    float ls0 = l0[0] + l0[1] + l0[2] + l0[3];
    ls0 += __shfl_xor(ls0, 16); ls0 += __shfl_xor(ls0, 32);
    float ls1 = l1[0] + l1[1] + l1[2] + l1[3];
    ls1 += __shfl_xor(ls1, 16); ls1 += __shfl_xor(ls1, 32);

#pragma unroll
    for (int r = 0; r < 4; ++r) {
        o_s[wave][quad * 4 + r][l16]           = o00[r];
        o_s[wave][16 + quad * 4 + r][l16]      = o01[r];
        o_s[wave][quad * 4 + r][16 + l16]      = o10[r];
        o_s[wave][16 + quad * 4 + r][16 + l16] = o11[r];
    }
    if (quad == 0) { l_s[wave][l16] = ls0; l_s[wave][16 + l16] = ls1; }
    __syncthreads();

    // epilogue: 256 thr -> 32 q x 8 groups of 4 ch; q-major coalesced reads
    const int q = tid & 31;            // pixel within tile
    const int d0 = (tid >> 5) * 4;     // 4-channel group
    float l = l_s[0][q] + l_s[1][q] + l_s[2][q] + l_s[3][q];
    const float inv = 1.f / l;
    float v[4] = {0.f, 0.f, 0.f, 0.f};
#pragma unroll
    for (int w = 0; w < 4; ++w) {
#pragma unroll
        for (int j = 0; j < 4; ++j) v[j] += o_s[w][d0 + j][q];
    }
    const int n = qb + q;
    const int ch = h * HD + d0;

    // fused pe: 7x7 depthwise conv over v_bu for 4 channels at pixel n
    const int y = n / 48, x0 = n - y * 48;
    const size_t vb0 = ((size_t)b * NCH + ch) * NPIX;
    float pe[4];
#pragma unroll
    for (int j = 0; j < 4; ++j) pe[j] = pe_b[ch + j];
#pragma unroll
    for (int ky = 0; ky < 7; ++ky) {
        int yy = y + ky - 3;
        if ((unsigned)yy < 48u) {
#pragma unroll
            for (int kx = 0; kx < 7; ++kx) {
                int xx = x0 + kx - 3;
                if ((unsigned)xx < 48u) {
                    const int off = yy * 48 + xx;
                    const int wko = ky * 7 + kx;
#pragma unroll
                    for (int j = 0; j < 4; ++j)
                        pe[j] += pe_w[(ch + j) * 49 + wko] * v_bu[vb0 + (size_t)j * NPIX + off];
                }
            }
        }
    }

    union { __bf16 hh[4]; uint2 u; } pk;
#pragma unroll
    for (int j = 0; j < 4; ++j) pk.hh[j] = (__bf16)(v[j] * inv + pe[j]);
    *(uint2*)&opb[((size_t)b * NPIX + n) * NCH + ch] = pk.u;
}

// ---------------- merged MLP tail (round-3 best-measured version) ------------
__global__ __launch_bounds__(512, 2) void mlp_k(
    const __bf16* __restrict__ opb, const __bf16* __restrict__ Wp,
    const __bf16* __restrict__ W1, const __bf16* __restrict__ W2,
    const float* __restrict__ pj_b, const float* __restrict__ f1_b,
    const float* __restrict__ f2_b, const float* __restrict__ x,
    float* __restrict__ out) {
    const int tid = threadIdx.x;
    const int wave = tid >> 6, lane = tid & 63;
    const int l16 = lane & 15, quad = lane >> 4;
    const int b = (int)blockIdx.x / 144;
    const int m0 = ((int)blockIdx.x % 144) * 16;

    __shared__ __bf16 x1h[16][264];    // +8 bf16 pad
    __shared__ __bf16 hh[16][520];     // +8 bf16 pad

    const int oc_a = wave * 16 + l16;          // tile w
    const int oc_b = oc_a + 128;               // tile w+8
    const int row = quad * 4;
    const int mq = m0 + quad * 4;

    // ---- phase A: proj + bias + residual(x) -> x1 (regs f32 + LDS bf16) ----
    const __bf16* aptr = opb + ((size_t)b * NPIX + m0 + l16) * NCH + quad * 8;
    const __bf16* wp0 = Wp + (size_t)oc_a * NCH + quad * 8;
    const __bf16* wp1 = Wp + (size_t)oc_b * NCH + quad * 8;
    f32x4 a0 = {0.f, 0.f, 0.f, 0.f}, a1 = {0.f, 0.f, 0.f, 0.f};
#pragma unroll
    for (int k = 0; k < NCH; k += 32) {
        bf16x8 af = *(const bf16x8*)(aptr + k);
        a0 = __builtin_amdgcn_mfma_f32_16x16x32_bf16(af, *(const bf16x8*)(wp0 + k), a0, 0, 0, 0);
        a1 = __builtin_amdgcn_mfma_f32_16x16x32_bf16(af, *(const bf16x8*)(wp1 + k), a1, 0, 0, 0);
    }
    float x1r0[4], x1r1[4];
    {
        const float bb0 = pj_b[oc_a], bb1 = pj_b[oc_b];
        float4 xr0 = *(const float4*)&x[((size_t)b * NCH + oc_a) * NPIX + mq];
        float4 xr1 = *(const float4*)&x[((size_t)b * NCH + oc_b) * NPIX + mq];
        const float* xp0 = &xr0.x;
        const float* xp1 = &xr1.x;
#pragma unroll
        for (int r = 0; r < 4; ++r) {
            float v0 = a0[r] + bb0 + xp0[r];
            float v1 = a1[r] + bb1 + xp1[r];
            x1r0[r] = v0; x1r1[r] = v1;
            x1h[row + r][oc_a] = (__bf16)v0;
            x1h[row + r][oc_b] = (__bf16)v1;
        }
    }
    __syncthreads();

    // ---- phase B: h = silu(fc1(x1)) -> LDS bf16; 4 oc-tiles per wave ----
    {
        const __bf16* w10 = W1 + (size_t)oc_a * NCH + quad * 8;
        const __bf16* w11 = W1 + (size_t)(oc_a + 128) * NCH + quad * 8;
        const __bf16* w12 = W1 + (size_t)(oc_a + 256) * NCH + quad * 8;
        const __bf16* w13 = W1 + (size_t)(oc_a + 384) * NCH + quad * 8;
        f32x4 c0 = {0.f, 0.f, 0.f, 0.f}, c1 = {0.f, 0.f, 0.f, 0.f};
        f32x4 c2 = {0.f, 0.f, 0.f, 0.f}, c3 = {0.f, 0.f, 0.f, 0.f};
#pragma unroll
        for (int k = 0; k < NCH; k += 32) {
            bf16x8 af = *(const bf16x8*)&x1h[l16][quad * 8 + k];
            c0 = __builtin_amdgcn_mfma_f32_16x16x32_bf16(af, *(const bf16x8*)(w10 + k), c0, 0, 0, 0);
            c1 = __builtin_amdgcn_mfma_f32_16x16x32_bf16(af, *(const bf16x8*)(w11 + k), c1, 0, 0, 0);
            c2 = __builtin_amdgcn_mfma_f32_16x16x32_bf16(af, *(const bf16x8*)(w12 + k), c2, 0, 0, 0);
            c3 = __builtin_amdgcn_mfma_f32_16x16x32_bf16(af, *(const bf16x8*)(w13 + k), c3, 0, 0, 0);
        }
        const float g0 = f1_b[oc_a], g1 = f1_b[oc_a + 128];
        const float g2 = f1_b[oc_a + 256], g3 = f1_b[oc_a + 384];
#pragma unroll
        for (int r = 0; r < 4; ++r) {
            float v0 = c0[r] + g0; v0 = v0 / (1.f + __expf(-v0));
            float v1 = c1[r] + g1; v1 = v1 / (1.f + __expf(-v1));
            float v2 = c2[r] + g2; v2 = v2 / (1.f + __expf(-v2));
            float v3 = c3[r] + g3; v3 = v3 / (1.f + __expf(-v3));
            hh[row + r][oc_a]       = (__bf16)v0;
            hh[row + r][oc_a + 128] = (__bf16)v1;
            hh[row + r][oc_a + 256] = (__bf16)v2;
            hh[row + r][oc_a + 384] = (__bf16)v3;
        }
    }
    __syncthreads();

    // ---- phase C: out = x1 + fc2(h) -> NCHW f32; 2 oc-tiles per wave ----
    {
        const __bf16* w20 = W2 + (size_t)oc_a * H1DIM + quad * 8;
        const __bf16* w21 = W2 + (size_t)oc_b * H1DIM + quad * 8;
        f32x4 d0 = {0.f, 0.f, 0.f, 0.f}, d1 = {0.f, 0.f, 0.f, 0.f};
#pragma unroll
        for (int k = 0; k < H1DIM; k += 32) {
            bf16x8 af = *(const bf16x8*)&hh[l16][quad * 8 + k];
            d0 = __builtin_amdgcn_mfma_f32_16x16x32_bf16(af, *(const bf16x8*)(w20 + k), d0, 0, 0, 0);
            d1 = __builtin_amdgcn_mfma_f32_16x16x32_bf16(af, *(const bf16x8*)(w21 + k), d1, 0, 0, 0);
        }
        const float g0 = f2_b[oc_a], g1 = f2_b[oc_b];
        float4 o0, o1;
        float* p0 = &o0.x; float* p1 = &o1.x;
#pragma unroll
        for (int r = 0; r < 4; ++r) {
            p0[r] = d0[r] + g0 + x1r0[r];
            p1[r] = d1[r] + g1 + x1r1[r];
        }
        *(float4*)&out[((size_t)b * NCH + oc_a) * NPIX + mq] = o0;
        *(float4*)&out[((size_t)b * NCH + oc_b) * NPIX + mq] = o1;
    }
}

extern "C" void kernel_launch(void* const* d_in, const int* in_sizes, int n_in,
                              void* d_out, int out_size, void* d_ws, size_t ws_size,
                              hipStream_t stream) {
    const float* x    = (const float*)d_in[0];
    const float* qk_w = (const float*)d_in[1];
    const float* qk_b = (const float*)d_in[2];
    const float* v_w  = (const float*)d_in[3];
    const float* v_b  = (const float*)d_in[4];
    const float* pe_w = (const float*)d_in[5];
    const float* pe_b = (const float*)d_in[6];
    const float* pj_w = (const float*)d_in[7];
    const float* pj_b = (const float*)d_in[8];
    const float* f1_w = (const float*)d_in[9];
    const float* f1_b = (const float*)d_in[10];
    const float* f2_w = (const float*)d_in[11];
    const float* f2_b = (const float*)d_in[12];
    float* out = (float*)d_out;

    const int B = 2;
    const size_t plane = (size_t)NCH * NPIX;       // 589824
    const size_t bp = (size_t)B * plane;           // 1179648

    float* v_bu  = (float*)d_ws;                   // NCHW f32 (v conv output)
    __bf16* opb  = (__bf16*)(v_bu + bp);           // NHWC bf16 (attn+pe)
    __bf16* Qb   = opb + bp;                       // [bh][n][32] (pre-scaled)
    __bf16* Kf   = Qb + bp;                        // QK A-frag tiles
    __bf16* Vf   = Kf + bp;                        // PV A-frag tiles
    __bf16* Wall = Vf + bp;                        // mlp-tail weights, 327680 bf16
    __bf16* Wp = Wall;                             // 65536
    __bf16* W1 = Wall + 65536;                     // 131072
    __bf16* W2 = Wall + 196608;                    // 131072

    // 1) qk+v conv directly from NCHW f32 x (inline transpose+cast) + v->v_bu;
    //    blocks >=3456 cast mlp-tail weights. prep_k dispatch eliminated.
    qkv2_k<<<3776, 256, 0, stream>>>(x, qk_w, v_w, qk_b, v_b, pj_w, f1_w, f2_w,
                                     Qb, Kf, v_bu, Vf, Wall);
    // 2) attention v9: key-split 4, setprio; fused dwconv-pe epilogue
    attn9_k<<<1152, 256, 0, stream>>>(Qb, Kf, Vf, v_bu, pe_w, pe_b, opb);
    // 3) merged MLP tail: proj -> fc1 -> fc2, block-local via LDS
    mlp_k<<<288, 512, 0, stream>>>(opb, Wp, W1, W2, pj_b, f1_b, f2_b, x, out);
}

// Round 12
// 189.503 us; speedup vs baseline: 1.0507x; 1.0507x over previous
//
#include <hip/hip_runtime.h>
#include <hip/hip_bf16.h>

#define NCH 256      // C
#define NHD 8        // heads
#define HD 32        // head dim
#define NPIX 2304    // 48*48
#define H1DIM 512

typedef __attribute__((ext_vector_type(8))) __bf16 bf16x8;
typedef __attribute__((ext_vector_type(4))) float f32x4;

// ---------------- prep: x NCHW f32 -> NHWC bf16  +  weight cast --------------
// blocks [0,288): transpose;  blocks [288,800): weight cast (5 matrices)
// NOTE (R11): folding this into qkv regressed (+10 us) — strided f32 A-builds
// in qkv's inner loop cost more than this dispatch. Keep separate.
__global__ __launch_bounds__(256) void prep_k(
    const float* __restrict__ x,
    const float* __restrict__ w0, const float* __restrict__ w1,
    const float* __restrict__ w2, const float* __restrict__ w3,
    const float* __restrict__ w4,
    __bf16* __restrict__ Xb, __bf16* __restrict__ Wall) {
    const int tid = threadIdx.x;
    if (blockIdx.x < 288) {
        const int t = blockIdx.x;
        const int b = t / 144, r0 = t % 144;
        const int c0 = (r0 / 36) * 64, n0 = (r0 % 36) * 64;
        __shared__ float tile[64][65];
        const size_t sb = ((size_t)b * NCH + c0) * NPIX + n0;
#pragma unroll
        for (int i = 0; i < 16; ++i) {
            int idx = tid + i * 256;
            int rr = idx >> 6, cc = idx & 63;
            tile[rr][cc] = x[sb + (size_t)rr * NPIX + cc];
        }
        __syncthreads();
#pragma unroll
        for (int i = 0; i < 8; ++i) {
            int idx = tid + i * 256;
            int nn = idx >> 5, cp = (idx & 31) * 2;
            union { __bf16 h[2]; unsigned u; } pk;
            pk.h[0] = (__bf16)tile[cp][nn];
            pk.h[1] = (__bf16)tile[cp + 1][nn];
            *(unsigned*)&Xb[((size_t)b * NPIX + n0 + nn) * NCH + c0 + cp] = pk.u;
        }
    } else {
        int i = (blockIdx.x - 288) * 256 + tid;   // float4 index over 131072
        const float* src; int off;
        if (i < 32768)      { src = w0; off = i; }
        else if (i < 49152) { src = w1; off = i - 32768; }
        else if (i < 65536) { src = w2; off = i - 49152; }
        else if (i < 98304) { src = w3; off = i - 65536; }
        else                { src = w4; off = i - 98304; }
        float4 v = ((const float4*)src)[off];
        union { __bf16 h[4]; uint2 u; } pk;
        pk.h[0] = (__bf16)v.x; pk.h[1] = (__bf16)v.y;
        pk.h[2] = (__bf16)v.z; pk.h[3] = (__bf16)v.w;
        ((uint2*)Wall)[i] = pk.u;
    }
}

// ---------------- fused qk+v conv, head-pinned to XCD (bid&7 = head) ---------
__global__ __launch_bounds__(256) void qkv_k(
    const __bf16* __restrict__ A, const __bf16* __restrict__ Wq,
    const __bf16* __restrict__ Wv, const float* __restrict__ qk_b,
    const float* __restrict__ v_b, __bf16* __restrict__ Qb,
    __bf16* __restrict__ Kf, float* __restrict__ v_bu,
    __bf16* __restrict__ Vf) {
    const int tid = threadIdx.x;
    const int wave = tid >> 6, lane = tid & 63;
    const int l16 = lane & 15, quad = lane >> 4;
    const int h = blockIdx.x & 7;
    const int u = blockIdx.x >> 3;        // [0,432)
    const int tau = u * 4 + wave;         // [0,1728)
    const int px = tau % 144;
    const int rest = tau / 144;           // [0,12)
    const int b = rest & 1;
    const int sub = rest >> 1;            // [0,6)
    const int m0 = px * 16;
    const bool isv = sub >= 4;
    const int oc0 = isv ? (32 * h + 16 * (sub - 4)) : (64 * h + 16 * sub);
    const __bf16* W = isv ? Wv : Wq;

    const __bf16* aptr = A + ((size_t)b * NPIX + m0 + l16) * NCH + quad * 8;
    const __bf16* bptr = W + (size_t)(oc0 + l16) * NCH + quad * 8;

    f32x4 acc = {0.f, 0.f, 0.f, 0.f};
#pragma unroll 8
    for (int k = 0; k < NCH; k += 32) {
        bf16x8 af = *(const bf16x8*)(aptr + k);
        bf16x8 bf = *(const bf16x8*)(bptr + k);
        acc = __builtin_amdgcn_mfma_f32_16x16x32_bf16(af, bf, acc, 0, 0, 0);
    }

    const int oc = oc0 + l16;
    const int mb = m0 + quad * 4;

    if (!isv) {
        const float bb = qk_b[oc];
        const int bh = b * NHD + h;
        const int dd = (oc0 & 16) + l16;
        if ((oc0 & 32) == 0) {
            const float qs = 0.17677669529663689f * 1.4426950408889634f;  // hd^-0.5 * log2e
#pragma unroll
            for (int r = 0; r < 4; ++r)
                Qb[((size_t)bh * NPIX + mb + r) * 32 + dd] = (__bf16)((acc[r] + bb) * qs);
        } else {
            __bf16* kp = Kf + ((size_t)(bh * 144 + px) * 64 + (dd >> 3) * 16 + quad * 4) * 8 + (dd & 7);
#pragma unroll
            for (int r = 0; r < 4; ++r) kp[r * 8] = (__bf16)(acc[r] + bb);
        }
    } else {
        const float bb = v_b[oc];
        const int bh = b * NHD + h;
        const int half = (oc0 >> 4) & 1;
        const size_t fb = ((size_t)b * NCH + oc) * NPIX + mb;
        float4 vf_; float* vp = &vf_.x;
        union { __bf16 hh[4]; uint2 u; } pk;
#pragma unroll
        for (int r = 0; r < 4; ++r) {
            float v = acc[r] + bb;
            vp[r] = v; pk.hh[r] = (__bf16)v;
        }
        *(float4*)&v_bu[fb] = vf_;
        *(uint2*)&Vf[((size_t)(bh * 144 + px) * 64 + lane) * 8 + half * 4] = pk.u;
    }
}

// ---------------- MFMA flash attention (QBLK=32) + dwconv-pe epilogue --------
// in-WG key-split 8, head-pinned; s_setprio(1) around MFMA clusters (T5,
// measured win in R9: VGPR 52->36, occupancy 30->43%, best total 189.6).
__global__ __launch_bounds__(512) void attn7_k(const __bf16* __restrict__ Qb,
                                               const __bf16* __restrict__ Kf,
                                               const __bf16* __restrict__ Vf,
                                               const float* __restrict__ v_bu,
                                               const float* __restrict__ pe_w,
                                               const float* __restrict__ pe_b,
                                               __bf16* __restrict__ opb) {
    const int tid = threadIdx.x;
    const int wave = tid >> 6, lane = tid & 63;
    const int l16 = lane & 15, quad = lane >> 4;
    const int h = blockIdx.x & 7;
    const int r0 = (int)blockIdx.x >> 3;   // [0,144)
    const int qt = r0 % 72;
    const int b = r0 / 72;
    const int qb = qt * 32;
    const int bh = b * NHD + h;

    __shared__ float o_s[8][32][33];   // [wave][d][q], pad 33 -> <=2-way conflicts
    __shared__ float l_s[8][32];       // [wave][q]

    bf16x8 b_q0 = *(const bf16x8*)(Qb + ((size_t)bh * NPIX + qb + l16) * 32 + quad * 8);
    bf16x8 b_q1 = *(const bf16x8*)(Qb + ((size_t)bh * NPIX + qb + 16 + l16) * 32 + quad * 8);

    const __bf16* kf = Kf + ((size_t)(bh * 144 + wave * 18) * 64 + lane) * 8;
    const __bf16* vf = Vf + ((size_t)(bh * 144 + wave * 18) * 64 + lane) * 8;

    f32x4 o00 = {0.f,0.f,0.f,0.f}, o01 = {0.f,0.f,0.f,0.f};
    f32x4 o10 = {0.f,0.f,0.f,0.f}, o11 = {0.f,0.f,0.f,0.f};
    f32x4 l0 = {0.f,0.f,0.f,0.f}, l1 = {0.f,0.f,0.f,0.f};

#pragma unroll 3
    for (int t = 0; t < 18; ++t) {
        bf16x8 a_k = *(const bf16x8*)(kf + (size_t)t * 512);
        bf16x8 va  = *(const bf16x8*)(vf + (size_t)t * 512);
        f32x4 z = {0.f, 0.f, 0.f, 0.f};
        __builtin_amdgcn_s_setprio(1);
        f32x4 s0 = __builtin_amdgcn_mfma_f32_16x16x32_bf16(a_k, b_q0, z, 0, 0, 0);
        f32x4 s1 = __builtin_amdgcn_mfma_f32_16x16x32_bf16(a_k, b_q1, z, 0, 0, 0);
        __builtin_amdgcn_s_setprio(0);
        f32x4 p0, p1;
#pragma unroll
        for (int r = 0; r < 4; ++r) {
            p0[r] = __builtin_amdgcn_exp2f(s0[r]);
            p1[r] = __builtin_amdgcn_exp2f(s1[r]);
        }
        l0 += p0; l1 += p1;
        bf16x8 b0lo = {}, b0hi = {}, b1lo = {}, b1hi = {};
#pragma unroll
        for (int r = 0; r < 4; ++r) {
            __bf16 c0 = (__bf16)p0[r], c1 = (__bf16)p1[r];
            b0lo[r] = c0; b0hi[4 + r] = c0;
            b1lo[r] = c1; b1hi[4 + r] = c1;
        }
        __builtin_amdgcn_s_setprio(1);
        o00 = __builtin_amdgcn_mfma_f32_16x16x32_bf16(va, b0lo, o00, 0, 0, 0);
        o01 = __builtin_amdgcn_mfma_f32_16x16x32_bf16(va, b0hi, o01, 0, 0, 0);
        o10 = __builtin_amdgcn_mfma_f32_16x16x32_bf16(va, b1lo, o10, 0, 0, 0);
        o11 = __builtin_amdgcn_mfma_f32_16x16x32_bf16(va, b1hi, o11, 0, 0, 0);
        __builtin_amdgcn_s_setprio(0);
    }

    float ls0 = l0[0] + l0[1] + l0[2] + l0[3];
    ls0 += __shfl_xor(ls0, 16); ls0 += __shfl_xor(ls0, 32);
    float ls1 = l1[0] + l1[1] + l1[2] + l1[3];
    ls1 += __shfl_xor(ls1, 16); ls1 += __shfl_xor(ls1, 32);

#pragma unroll
    for (int r = 0; r < 4; ++r) {
        o_s[wave][quad * 4 + r][l16]           = o00[r];
        o_s[wave][16 + quad * 4 + r][l16]      = o01[r];
        o_s[wave][quad * 4 + r][16 + l16]      = o10[r];
        o_s[wave][16 + quad * 4 + r][16 + l16] = o11[r];
    }
    if (quad == 0) { l_s[wave][l16] = ls0; l_s[wave][16 + l16] = ls1; }
    __syncthreads();

    // final: 512 thr -> 1024 (q,d)-pairs; q-major for coalesced v_bu reads
    const int q = tid & 31;            // pixel within tile
    const int d0 = (tid >> 5) * 2;     // channel pair
    float l = 0.f;
#pragma unroll
    for (int w = 0; w < 8; ++w) l += l_s[w][q];
    const float inv = 1.f / l;
    float v0 = 0.f, v1 = 0.f;
#pragma unroll
    for (int w = 0; w < 8; ++w) {
        v0 += o_s[w][d0][q];
        v1 += o_s[w][d0 + 1][q];
    }
    const int n = qb + q;
    const int ch = h * HD + d0;

    // ---- fused pe: 7x7 depthwise conv over v_bu at (ch, ch+1, pixel n) ----
    const int y = n / 48, x0 = n - y * 48;
    const size_t vb0 = ((size_t)b * NCH + ch) * NPIX;
    const float* wk0 = pe_w + ch * 49;
    const float* wk1 = wk0 + 49;
    float pe0 = pe_b[ch], pe1 = pe_b[ch + 1];
#pragma unroll
    for (int ky = 0; ky < 7; ++ky) {
        int yy = y + ky - 3;
        if ((unsigned)yy < 48u) {
#pragma unroll
            for (int kx = 0; kx < 7; ++kx) {
                int xx = x0 + kx - 3;
                if ((unsigned)xx < 48u) {
                    const int off = yy * 48 + xx;
                    pe0 += wk0[ky * 7 + kx] * v_bu[vb0 + off];
                    pe1 += wk1[ky * 7 + kx] * v_bu[vb0 + NPIX + off];
                }
            }
        }
    }

    v0 = v0 * inv + pe0;
    v1 = v1 * inv + pe1;
    union { __bf16 hh[2]; unsigned u; } pk;
    pk.hh[0] = (__bf16)v0; pk.hh[1] = (__bf16)v1;
    *(unsigned*)&opb[((size_t)b * NPIX + n) * NCH + ch] = pk.u;
}

// ---------------- merged MLP tail (round-3 best-measured version) ------------
__global__ __launch_bounds__(512, 2) void mlp_k(
    const __bf16* __restrict__ opb, const __bf16* __restrict__ Wp,
    const __bf16* __restrict__ W1, const __bf16* __restrict__ W2,
    const float* __restrict__ pj_b, const float* __restrict__ f1_b,
    const float* __restrict__ f2_b, const float* __restrict__ x,
    float* __restrict__ out) {
    const int tid = threadIdx.x;
    const int wave = tid >> 6, lane = tid & 63;
    const int l16 = lane & 15, quad = lane >> 4;
    const int b = (int)blockIdx.x / 144;
    const int m0 = ((int)blockIdx.x % 144) * 16;

    __shared__ __bf16 x1h[16][264];    // +8 bf16 pad
    __shared__ __bf16 hh[16][520];     // +8 bf16 pad

    const int oc_a = wave * 16 + l16;          // tile w
    const int oc_b = oc_a + 128;               // tile w+8
    const int row = quad * 4;
    const int mq = m0 + quad * 4;

    // ---- phase A: proj + bias + residual(x) -> x1 (regs f32 + LDS bf16) ----
    const __bf16* aptr = opb + ((size_t)b * NPIX + m0 + l16) * NCH + quad * 8;
    const __bf16* wp0 = Wp + (size_t)oc_a * NCH + quad * 8;
    const __bf16* wp1 = Wp + (size_t)oc_b * NCH + quad * 8;
    f32x4 a0 = {0.f, 0.f, 0.f, 0.f}, a1 = {0.f, 0.f, 0.f, 0.f};
#pragma unroll
    for (int k = 0; k < NCH; k += 32) {
        bf16x8 af = *(const bf16x8*)(aptr + k);
        a0 = __builtin_amdgcn_mfma_f32_16x16x32_bf16(af, *(const bf16x8*)(wp0 + k), a0, 0, 0, 0);
        a1 = __builtin_amdgcn_mfma_f32_16x16x32_bf16(af, *(const bf16x8*)(wp1 + k), a1, 0, 0, 0);
    }
    float x1r0[4], x1r1[4];
    {
        const float bb0 = pj_b[oc_a], bb1 = pj_b[oc_b];
        float4 xr0 = *(const float4*)&x[((size_t)b * NCH + oc_a) * NPIX + mq];
        float4 xr1 = *(const float4*)&x[((size_t)b * NCH + oc_b) * NPIX + mq];
        const float* xp0 = &xr0.x;
        const float* xp1 = &xr1.x;
#pragma unroll
        for (int r = 0; r < 4; ++r) {
            float v0 = a0[r] + bb0 + xp0[r];
            float v1 = a1[r] + bb1 + xp1[r];
            x1r0[r] = v0; x1r1[r] = v1;
            x1h[row + r][oc_a] = (__bf16)v0;
            x1h[row + r][oc_b] = (__bf16)v1;
        }
    }
    __syncthreads();

    // ---- phase B: h = silu(fc1(x1)) -> LDS bf16; 4 oc-tiles per wave ----
    {
        const __bf16* w10 = W1 + (size_t)oc_a * NCH + quad * 8;
        const __bf16* w11 = W1 + (size_t)(oc_a + 128) * NCH + quad * 8;
        const __bf16* w12 = W1 + (size_t)(oc_a + 256) * NCH + quad * 8;
        const __bf16* w13 = W1 + (size_t)(oc_a + 384) * NCH + quad * 8;
        f32x4 c0 = {0.f, 0.f, 0.f, 0.f}, c1 = {0.f, 0.f, 0.f, 0.f};
        f32x4 c2 = {0.f, 0.f, 0.f, 0.f}, c3 = {0.f, 0.f, 0.f, 0.f};
#pragma unroll
        for (int k = 0; k < NCH; k += 32) {
            bf16x8 af = *(const bf16x8*)&x1h[l16][quad * 8 + k];
            c0 = __builtin_amdgcn_mfma_f32_16x16x32_bf16(af, *(const bf16x8*)(w10 + k), c0, 0, 0, 0);
            c1 = __builtin_amdgcn_mfma_f32_16x16x32_bf16(af, *(const bf16x8*)(w11 + k), c1, 0, 0, 0);
            c2 = __builtin_amdgcn_mfma_f32_16x16x32_bf16(af, *(const bf16x8*)(w12 + k), c2, 0, 0, 0);
            c3 = __builtin_amdgcn_mfma_f32_16x16x32_bf16(af, *(const bf16x8*)(w13 + k), c3, 0, 0, 0);
        }
        const float g0 = f1_b[oc_a], g1 = f1_b[oc_a + 128];
        const float g2 = f1_b[oc_a + 256], g3 = f1_b[oc_a + 384];
#pragma unroll
        for (int r = 0; r < 4; ++r) {
            float v0 = c0[r] + g0; v0 = v0 / (1.f + __expf(-v0));
            float v1 = c1[r] + g1; v1 = v1 / (1.f + __expf(-v1));
            float v2 = c2[r] + g2; v2 = v2 / (1.f + __expf(-v2));
            float v3 = c3[r] + g3; v3 = v3 / (1.f + __expf(-v3));
            hh[row + r][oc_a]       = (__bf16)v0;
            hh[row + r][oc_a + 128] = (__bf16)v1;
            hh[row + r][oc_a + 256] = (__bf16)v2;
            hh[row + r][oc_a + 384] = (__bf16)v3;
        }
    }
    __syncthreads();

    // ---- phase C: out = x1 + fc2(h) -> NCHW f32; 2 oc-tiles per wave ----
    {
        const __bf16* w20 = W2 + (size_t)oc_a * H1DIM + quad * 8;
        const __bf16* w21 = W2 + (size_t)oc_b * H1DIM + quad * 8;
        f32x4 d0 = {0.f, 0.f, 0.f, 0.f}, d1 = {0.f, 0.f, 0.f, 0.f};
#pragma unroll
        for (int k = 0; k < H1DIM; k += 32) {
            bf16x8 af = *(const bf16x8*)&hh[l16][quad * 8 + k];
            d0 = __builtin_amdgcn_mfma_f32_16x16x32_bf16(af, *(const bf16x8*)(w20 + k), d0, 0, 0, 0);
            d1 = __builtin_amdgcn_mfma_f32_16x16x32_bf16(af, *(const bf16x8*)(w21 + k), d1, 0, 0, 0);
        }
        const float g0 = f2_b[oc_a], g1 = f2_b[oc_b];
        float4 o0, o1;
        float* p0 = &o0.x; float* p1 = &o1.x;
#pragma unroll
        for (int r = 0; r < 4; ++r) {
            p0[r] = d0[r] + g0 + x1r0[r];
            p1[r] = d1[r] + g1 + x1r1[r];
        }
        *(float4*)&out[((size_t)b * NCH + oc_a) * NPIX + mq] = o0;
        *(float4*)&out[((size_t)b * NCH + oc_b) * NPIX + mq] = o1;
    }
}

extern "C" void kernel_launch(void* const* d_in, const int* in_sizes, int n_in,
                              void* d_out, int out_size, void* d_ws, size_t ws_size,
                              hipStream_t stream) {
    const float* x    = (const float*)d_in[0];
    const float* qk_w = (const float*)d_in[1];
    const float* qk_b = (const float*)d_in[2];
    const float* v_w  = (const float*)d_in[3];
    const float* v_b  = (const float*)d_in[4];
    const float* pe_w = (const float*)d_in[5];
    const float* pe_b = (const float*)d_in[6];
    const float* pj_w = (const float*)d_in[7];
    const float* pj_b = (const float*)d_in[8];
    const float* f1_w = (const float*)d_in[9];
    const float* f1_b = (const float*)d_in[10];
    const float* f2_w = (const float*)d_in[11];
    const float* f2_b = (const float*)d_in[12];
    float* out = (float*)d_out;

    const int B = 2;
    const size_t plane = (size_t)NCH * NPIX;       // 589824
    const size_t bp = (size_t)B * plane;           // 1179648

    float* v_bu  = (float*)d_ws;                   // NCHW f32 (v conv output)
    __bf16* Xb   = (__bf16*)(v_bu + bp);           // NHWC bf16 [b][n][256]
    __bf16* opb  = Xb + bp;                        // NHWC bf16 (attn+pe)
    __bf16* Qb   = opb + bp;                       // [bh][n][32] (pre-scaled)
    __bf16* Kf   = Qb + bp;                        // QK A-frag tiles
    __bf16* Vf   = Kf + bp;                        // PV A-frag tiles
    __bf16* Wall = Vf + bp;                        // 524288 bf16
    __bf16* Wq = Wall;
    __bf16* Wv = Wall + 131072;
    __bf16* Wp = Wall + 196608;
    __bf16* W1 = Wall + 262144;
    __bf16* W2 = Wall + 393216;

    // 1) x transpose + all weight casts
    prep_k<<<800, 256, 0, stream>>>(x, qk_w, v_w, pj_w, f1_w, f2_w, Xb, Wall);
    // 2) qk conv (-> Qb, Kf) + v conv (-> v_bu f32, Vf), head-pinned
    qkv_k<<<3456, 256, 0, stream>>>(Xb, Wq, Wv, qk_b, v_b, Qb, Kf, v_bu, Vf);
    // 3) attention (QBLK=32) + dwconv-pe epilogue, setprio on MFMA clusters
    attn7_k<<<1152, 512, 0, stream>>>(Qb, Kf, Vf, v_bu, pe_w, pe_b, opb);
    // 4) merged MLP tail: proj -> fc1 -> fc2, block-local via LDS
    mlp_k<<<288, 512, 0, stream>>>(opb, Wp, W1, W2, pj_b, f1_b, f2_b, x, out);
}